// Round 1
// baseline (1110.154 us; speedup 1.0000x reference)
//
#include <hip/hip_runtime.h>
#include <hip/hip_bf16.h>

// QuantizedLinear: out[8192,11008] = x[8192,4096] @ dequant(W)^T
// W: 4-bit packed, groups of 128 along in_features, per-(out,group) zero+scale.

#define IN_F   4096
#define OUT_F  11008
#define M_DIM  8192
#define NGROUP 32

typedef __bf16 bf16x8 __attribute__((ext_vector_type(8)));
typedef float  f32x4  __attribute__((ext_vector_type(4)));
typedef unsigned short u16;
typedef u16 u16x8v __attribute__((ext_vector_type(8)));

__device__ __forceinline__ u16 f2bf(float f) {
  union { float f; unsigned u; } v; v.f = f;
  unsigned u = v.u;
  return (u16)((u + 0x7fffu + ((u >> 16) & 1u)) >> 16);  // RNE
}

__device__ __forceinline__ void gload_lds16(const void* gsrc, void* ldst) {
  __builtin_amdgcn_global_load_lds(
      (const __attribute__((address_space(1))) void*)gsrc,
      (__attribute__((address_space(3))) void*)ldst, 16, 0, 0);
}

// ---------------- dequant: packed int32 (1 byte each) -> bf16 W[out][in] ----
__global__ __launch_bounds__(256) void dequant_w(const int* __restrict__ qw,
                                                 const int* __restrict__ qz,
                                                 const float* __restrict__ sc,
                                                 u16* __restrict__ W) {
  const int total = (IN_F / 2) * OUT_F / 4;  // int4 chunks = 5,636,096
  int stride = gridDim.x * blockDim.x;
  for (int idx = blockIdx.x * blockDim.x + threadIdx.x; idx < total; idx += stride) {
    int j = idx << 2;             // first int32 index; row o has IN_F/2=2048 int32s
    int o = j >> 11;              // j / 2048
    int g = (j >> 6) & 31;        // (j % 2048) / 64 : 4 consecutive ints share a group
    float z = (float)qz[(o << 5) + g];
    float s = sc[(o << 5) + g];
    int4 q = ((const int4*)qw)[idx];
    int qs0 = q.x, qs1 = q.y, qs2 = q.z, qs3 = q.w;
    u16x8v w;
    w[0] = f2bf(((float)(qs0 & 15) - z) * s);
    w[1] = f2bf(((float)((qs0 >> 4) & 15) - z) * s);
    w[2] = f2bf(((float)(qs1 & 15) - z) * s);
    w[3] = f2bf(((float)((qs1 >> 4) & 15) - z) * s);
    w[4] = f2bf(((float)(qs2 & 15) - z) * s);
    w[5] = f2bf(((float)((qs2 >> 4) & 15) - z) * s);
    w[6] = f2bf(((float)(qs3 & 15) - z) * s);
    w[7] = f2bf(((float)((qs3 >> 4) & 15) - z) * s);
    ((u16x8v*)W)[idx] = w;        // flat bf16 index 2*j .. 2*j+7
  }
}

// ---------------- x fp32 -> bf16 -------------------------------------------
__global__ __launch_bounds__(256) void cvt_x(const float* __restrict__ x,
                                             u16* __restrict__ Xb) {
  const int total = M_DIM * IN_F / 8;  // 4,194,304
  int stride = gridDim.x * blockDim.x;
  for (int idx = blockIdx.x * blockDim.x + threadIdx.x; idx < total; idx += stride) {
    float4 a = ((const float4*)x)[idx * 2];
    float4 b = ((const float4*)x)[idx * 2 + 1];
    u16x8v v;
    v[0] = f2bf(a.x); v[1] = f2bf(a.y); v[2] = f2bf(a.z); v[3] = f2bf(a.w);
    v[4] = f2bf(b.x); v[5] = f2bf(b.y); v[6] = f2bf(b.z); v[7] = f2bf(b.w);
    ((u16x8v*)Xb)[idx] = v;
  }
}

// ---------------- bf16 GEMM: C[m,n] = sum_k A[m,k]*B[n,k] ------------------
// 128x128 tile, BK=32, 4 waves in 2x2 (each wave 64x64 = 4x4 frags of 16x16),
// global_load_lds width-16 staging (m97 structure), mfma_f32_16x16x32_bf16.
__global__ __launch_bounds__(256, 2) void gemm_bt(const u16* __restrict__ A,
                                                  const u16* __restrict__ B,
                                                  float* __restrict__ C) {
  constexpr int K = IN_F, N = OUT_F;
  constexpr int BK = 32;
  __shared__ __align__(16) u16 As[128 * BK];
  __shared__ __align__(16) u16 Bs[128 * BK];

  const int NTN = OUT_F / 128;               // 86
  const int NWG = (M_DIM / 128) * NTN;       // 5504 (divisible by 8)
  int bid = blockIdx.x;
  int wg = (bid & 7) * (NWG / 8) + (bid >> 3);  // bijective XCD swizzle
  int tm = wg / NTN, tn = wg % NTN;
  int m0 = tm * 128, n0 = tn * 128;

  int tid = threadIdx.x;
  int wave = tid >> 6, lane = tid & 63;
  int wr = wave >> 1, wc = wave & 1;

  // staging: wave covers rows wave*32 .. +31 (two 16-row issues).
  // lane l -> row +l/4, cols (l%4)*8 .. +7  (LDS dest = wave-uniform base + lane*16)
  const u16* aG = A + (size_t)(m0 + wave * 32 + (lane >> 2)) * K + ((lane & 3) << 3);
  const u16* bG = B + (size_t)(n0 + wave * 32 + (lane >> 2)) * K + ((lane & 3) << 3);
  u16* aL0 = As + (wave * 32) * BK;
  u16* aL1 = As + (wave * 32 + 16) * BK;
  u16* bL0 = Bs + (wave * 32) * BK;
  u16* bL1 = Bs + (wave * 32 + 16) * BK;
  const size_t rs = (size_t)16 * K;

  f32x4 acc[4][4] = {};

  // fragment base: lane l reads row (l&15), k-offset (l>>4)*8 (8 contiguous bf16)
  const u16* aF = As + (wr * 64 + (lane & 15)) * BK + ((lane >> 4) << 3);
  const u16* bF = Bs + (wc * 64 + (lane & 15)) * BK + ((lane >> 4) << 3);

  for (int k0 = 0; k0 < K; k0 += BK) {
    gload_lds16(aG, aL0);
    gload_lds16(aG + rs, aL1);
    gload_lds16(bG, bL0);
    gload_lds16(bG + rs, bL1);
    aG += BK; bG += BK;
    __syncthreads();   // compiler drains vmcnt before barrier -> tiles ready
    bf16x8 av[4], bv[4];
#pragma unroll
    for (int i = 0; i < 4; i++) av[i] = *(const bf16x8*)(aF + i * 16 * BK);
#pragma unroll
    for (int i = 0; i < 4; i++) bv[i] = *(const bf16x8*)(bF + i * 16 * BK);
#pragma unroll
    for (int mb = 0; mb < 4; mb++)
#pragma unroll
      for (int nb = 0; nb < 4; nb++)
        acc[mb][nb] = __builtin_amdgcn_mfma_f32_16x16x32_bf16(av[mb], bv[nb],
                                                              acc[mb][nb], 0, 0, 0);
    __syncthreads();   // all waves done reading before next stage overwrites
  }

  // C/D layout (m89-verified): col = lane&15, row = (lane>>4)*4 + j
  float* Cp = C + (size_t)(m0 + wr * 64 + ((lane >> 4) << 2)) * N + n0 + wc * 64 + (lane & 15);
#pragma unroll
  for (int mb = 0; mb < 4; mb++)
#pragma unroll
    for (int nb = 0; nb < 4; nb++)
#pragma unroll
      for (int j = 0; j < 4; j++)
        Cp[(size_t)(mb * 16 + j) * N + nb * 16] = acc[mb][nb][j];
}

// ---------------- exact fp32 fallback (only if ws too small) ---------------
__global__ __launch_bounds__(256) void naive_gemm(const float* __restrict__ x,
                                                  const int* __restrict__ qw,
                                                  const int* __restrict__ qz,
                                                  const float* __restrict__ sc,
                                                  float* __restrict__ out) {
  __shared__ float xs[IN_F];
  int m = blockIdx.y;
  int n = blockIdx.x * 256 + threadIdx.x;
  for (int i = threadIdx.x; i < IN_F; i += 256) xs[i] = x[(size_t)m * IN_F + i];
  __syncthreads();
  float acc = 0.f;
  const int* qrow = qw + (size_t)n * (IN_F / 2);
  for (int g = 0; g < NGROUP; g++) {
    float z = (float)qz[n * NGROUP + g];
    float s = sc[n * NGROUP + g];
    for (int t = 0; t < 64; t++) {
      int q = qrow[g * 64 + t];
      acc += xs[g * 128 + 2 * t] * ((float)(q & 15) - z) * s;
      acc += xs[g * 128 + 2 * t + 1] * ((float)((q >> 4) & 15) - z) * s;
    }
  }
  out[(size_t)m * OUT_F + n] = acc;
}

extern "C" void kernel_launch(void* const* d_in, const int* in_sizes, int n_in,
                              void* d_out, int out_size, void* d_ws, size_t ws_size,
                              hipStream_t stream) {
  const float* x  = (const float*)d_in[0];
  const int*   qw = (const int*)d_in[1];
  const int*   qz = (const int*)d_in[2];
  const float* sc = (const float*)d_in[3];
  float* out = (float*)d_out;

  const size_t WBYTES = (size_t)OUT_F * IN_F * 2;  // 90,177,536
  const size_t XBYTES = (size_t)M_DIM * IN_F * 2;  // 67,108,864

  if (ws_size >= WBYTES + XBYTES) {
    u16* Wb = (u16*)d_ws;
    u16* Xb = (u16*)((char*)d_ws + WBYTES);
    dequant_w<<<2048, 256, 0, stream>>>(qw, qz, sc, Wb);
    cvt_x<<<2048, 256, 0, stream>>>(x, Xb);
    gemm_bt<<<(M_DIM / 128) * (OUT_F / 128), 256, 0, stream>>>(Xb, Wb, out);
  } else {
    naive_gemm<<<dim3(OUT_F / 256, M_DIM), 256, 0, stream>>>(x, qw, qz, sc, out);
  }
}

// Round 2
// 771.928 us; speedup vs baseline: 1.4382x; 1.4382x over previous
//
#include <hip/hip_runtime.h>
#include <hip/hip_bf16.h>

// QuantizedLinear: out[8192,11008] = x[8192,4096] @ dequant(W)^T
// Round 2: 256x256 8-phase GEMM template (T2 swizzle + T3/T4 counted vmcnt + T5 setprio).

#define IN_F   4096
#define OUT_F  11008
#define M_DIM  8192
#define NGROUP 32

typedef __bf16 bf16x8 __attribute__((ext_vector_type(8)));
typedef float  f32x4  __attribute__((ext_vector_type(4)));
typedef unsigned short u16;
typedef u16 u16x8v __attribute__((ext_vector_type(8)));

__device__ __forceinline__ u16 f2bf(float f) {
  union { float f; unsigned u; } v; v.f = f;
  unsigned u = v.u;
  return (u16)((u + 0x7fffu + ((u >> 16) & 1u)) >> 16);  // RNE
}

__device__ __forceinline__ void gload_lds16(const void* gsrc, void* ldst) {
  __builtin_amdgcn_global_load_lds(
      (const __attribute__((address_space(1))) void*)gsrc,
      (__attribute__((address_space(3))) void*)ldst, 16, 0, 0);
}

// ---------------- dequant: packed 4-bit -> bf16 W[out][in] -----------------
__global__ __launch_bounds__(256) void dequant_w(const int* __restrict__ qw,
                                                 const int* __restrict__ qz,
                                                 const float* __restrict__ sc,
                                                 u16* __restrict__ W) {
  const int total = (IN_F / 2) * OUT_F / 4;  // int4 chunks
  int stride = gridDim.x * blockDim.x;
  for (int idx = blockIdx.x * blockDim.x + threadIdx.x; idx < total; idx += stride) {
    int j = idx << 2;
    int o = j >> 11;
    int g = (j >> 6) & 31;
    float z = (float)qz[(o << 5) + g];
    float s = sc[(o << 5) + g];
    int4 q = ((const int4*)qw)[idx];
    int qs0 = q.x, qs1 = q.y, qs2 = q.z, qs3 = q.w;
    u16x8v w;
    w[0] = f2bf(((float)(qs0 & 15) - z) * s);
    w[1] = f2bf(((float)((qs0 >> 4) & 15) - z) * s);
    w[2] = f2bf(((float)(qs1 & 15) - z) * s);
    w[3] = f2bf(((float)((qs1 >> 4) & 15) - z) * s);
    w[4] = f2bf(((float)(qs2 & 15) - z) * s);
    w[5] = f2bf(((float)((qs2 >> 4) & 15) - z) * s);
    w[6] = f2bf(((float)(qs3 & 15) - z) * s);
    w[7] = f2bf(((float)((qs3 >> 4) & 15) - z) * s);
    ((u16x8v*)W)[idx] = w;
  }
}

// ---------------- x fp32 -> bf16 -------------------------------------------
__global__ __launch_bounds__(256) void cvt_x(const float* __restrict__ x,
                                             u16* __restrict__ Xb) {
  const int total = M_DIM * IN_F / 8;
  int stride = gridDim.x * blockDim.x;
  for (int idx = blockIdx.x * blockDim.x + threadIdx.x; idx < total; idx += stride) {
    float4 a = ((const float4*)x)[idx * 2];
    float4 b = ((const float4*)x)[idx * 2 + 1];
    u16x8v v;
    v[0] = f2bf(a.x); v[1] = f2bf(a.y); v[2] = f2bf(a.z); v[3] = f2bf(a.w);
    v[4] = f2bf(b.x); v[5] = f2bf(b.y); v[6] = f2bf(b.z); v[7] = f2bf(b.w);
    ((u16x8v*)Xb)[idx] = v;
  }
}

// ---------------- 256x256 8-phase bf16 GEMM: C = A * B^T -------------------
// 8 waves (2M x 4N), per-wave 128x64 output, BK=64, double-buffered 128KiB LDS,
// XOR swizzle: 16B slot s at row r holds logical slot s^(r&7) (both sides).

#define BAR       __builtin_amdgcn_s_barrier()
#define LGKM0     asm volatile("s_waitcnt lgkmcnt(0)" ::: "memory")
#define VMCNT4    asm volatile("s_waitcnt vmcnt(4)" ::: "memory")
#define PRIO(p)   __builtin_amdgcn_s_setprio(p)

__global__ __launch_bounds__(512, 2) void gemm256(const u16* __restrict__ A,
                                                  const u16* __restrict__ B,
                                                  float* __restrict__ C) {
  constexpr int K = IN_F, N = OUT_F;
  constexpr int NT = K / 64;  // 64 K-tiles
  __shared__ __align__(16) u16 sA[2][256 * 64];
  __shared__ __align__(16) u16 sB[2][256 * 64];

  const int NTN = OUT_F / 256;           // 43
  const int NWG = (M_DIM / 256) * NTN;   // 1376 (divisible by 8)
  int bid = blockIdx.x;
  int wg  = (bid & 7) * (NWG / 8) + (bid >> 3);  // bijective XCD swizzle
  int tm = wg / NTN, tn = wg - tm * NTN;
  int m0 = tm * 256, n0 = tn * 256;

  int tid  = threadIdx.x;
  int lane = tid & 63;
  int wave = tid >> 6;
  int wr = wave >> 2, wc = wave & 3;

  // staging: thread covers row (tid>>3) of a 64-row issue, phys 16B slot tid&7.
  // phys slot s at row r holds global col-slot s^(r&7)  (involution).
  int rstage = tid >> 3;                               // 0..63
  int gslot  = ((tid & 7) ^ (rstage & 7)) << 3;        // global col elem
  int ldsoff = rstage * 64 + ((tid & 7) << 3);         // linear LDS elem
  const u16* Ag = A + (size_t)(m0 + rstage) * K + gslot;
  const u16* Bg = B + (size_t)(n0 + rstage) * K + gslot;

#define STAGE_A(cb, h, kt) do {                                   \
    const u16* _g = Ag + (size_t)(h) * 128 * K + (kt) * 64;       \
    u16* _l = sA[cb] + (h) * 128 * 64 + ldsoff;                   \
    gload_lds16(_g, _l);                                          \
    gload_lds16(_g + (size_t)64 * K, _l + 64 * 64);               \
  } while (0)

#define STAGE_B(cb, h, kt) do {                                   \
    const u16* _g = Bg + (size_t)(h) * 128 * K + (kt) * 64;       \
    u16* _l = sB[cb] + (h) * 128 * 64 + ldsoff;                   \
    gload_lds16(_g, _l);                                          \
    gload_lds16(_g + (size_t)64 * K, _l + 64 * 64);               \
  } while (0)

  // fragment reads: lane reads row base+(lane&15), k-quad q=lane>>4, slice ks.
  // phys 16B slot = (ks*4+q) ^ (lane&7)   (row&7 == lane&7 for all our rows)
  int q8  = lane >> 4;
  int sl0 = ((q8 ^ (lane & 7)) << 3);            // ks=0, elems
  int sl1 = (((q8 | 4) ^ (lane & 7)) << 3);      // ks=1
  int abase = (wr * 128 + (lane & 15)) * 64;     // elems
  int bbase = (wc * 64 + (lane & 15)) * 64;

  bf16x8 a_[8], b0_[4], b1_[4];
  f32x4 acc[8][4] = {};

#define LDA(cb, mh) do {                                          \
    const u16* _p = sA[cb] + abase + (mh) * 4096;                 \
    a_[0] = *(const bf16x8*)(_p + sl0);                           \
    a_[1] = *(const bf16x8*)(_p + sl1);                           \
    a_[2] = *(const bf16x8*)(_p + 1024 + sl0);                    \
    a_[3] = *(const bf16x8*)(_p + 1024 + sl1);                    \
    a_[4] = *(const bf16x8*)(_p + 2048 + sl0);                    \
    a_[5] = *(const bf16x8*)(_p + 2048 + sl1);                    \
    a_[6] = *(const bf16x8*)(_p + 3072 + sl0);                    \
    a_[7] = *(const bf16x8*)(_p + 3072 + sl1);                    \
  } while (0)

#define LDB(cb, nh, dst) do {                                     \
    const u16* _p = sB[cb] + bbase + (nh) * 2048;                 \
    dst[0] = *(const bf16x8*)(_p + sl0);                          \
    dst[1] = *(const bf16x8*)(_p + sl1);                          \
    dst[2] = *(const bf16x8*)(_p + 1024 + sl0);                   \
    dst[3] = *(const bf16x8*)(_p + 1024 + sl1);                   \
  } while (0)

#define QUAD(mh, nh, bq) do {                                                  \
    _Pragma("unroll") for (int mf = 0; mf < 4; mf++)                           \
      _Pragma("unroll") for (int nf = 0; nf < 2; nf++) {                       \
        acc[(mh)*4+mf][(nh)*2+nf] = __builtin_amdgcn_mfma_f32_16x16x32_bf16(   \
            a_[mf*2+0], bq[nf*2+0], acc[(mh)*4+mf][(nh)*2+nf], 0, 0, 0);       \
        acc[(mh)*4+mf][(nh)*2+nf] = __builtin_amdgcn_mfma_f32_16x16x32_bf16(   \
            a_[mf*2+1], bq[nf*2+1], acc[(mh)*4+mf][(nh)*2+nf], 0, 0, 0);       \
      }                                                                        \
  } while (0)

  // 4 phases per K-tile. Staging schedule (liveness-verified):
  //  P0: stage A-half0 of tile u+1 -> buf c^1 (A region free since u-1.P2)
  //  P1: stage A-half1 of tile u+1 -> buf c^1
  //  P2: stage B-half0 of tile u+2 -> buf c    (B region free after u.P1)
  //  P3: stage B-half1 of tile u+2 -> buf c; vmcnt(4) keeps exactly the
  //      P2/P3 stages in flight across the barrier (tile u+1 fully landed).
#define TILE(c, u) do {                                           \
    int _ka = ((u) + 1) & (NT - 1), _kb = ((u) + 2) & (NT - 1);   \
    /* P0 */                                                      \
    LDA(c, 0); LDB(c, 0, b0_); STAGE_A((c) ^ 1, 0, _ka);          \
    BAR; LGKM0; PRIO(1); QUAD(0, 0, b0_); PRIO(0); BAR;           \
    /* P1 */                                                      \
    LDB(c, 1, b1_); STAGE_A((c) ^ 1, 1, _ka);                     \
    BAR; LGKM0; PRIO(1); QUAD(0, 1, b1_); PRIO(0); BAR;           \
    /* P2 */                                                      \
    LDA(c, 1); STAGE_B(c, 0, _kb);                                \
    BAR; LGKM0; PRIO(1); QUAD(1, 1, b1_); PRIO(0); BAR;           \
    /* P3 */                                                      \
    STAGE_B(c, 1, _kb);                                           \
    BAR; PRIO(1); QUAD(1, 0, b0_); PRIO(0); VMCNT4; BAR;          \
  } while (0)

  // prologue: tile0 (A+B) -> buf0, tile1 B -> buf1; allow last 4 loads in flight
  STAGE_A(0, 0, 0); STAGE_A(0, 1, 0);
  STAGE_B(0, 0, 0); STAGE_B(0, 1, 0);
  STAGE_B(1, 0, 1); STAGE_B(1, 1, 1);
  VMCNT4; BAR;

#pragma unroll 1
  for (int u = 0; u < NT; u += 2) {
    TILE(0, u);
    TILE(1, u + 1);
  }

  // C/D layout: col = lane&15, row = (lane>>4)*4 + j
  float* Cp = C + (size_t)(m0 + wr * 128 + ((lane >> 4) << 2)) * N + n0 + wc * 64 + (lane & 15);
#pragma unroll
  for (int m = 0; m < 8; m++)
#pragma unroll
    for (int n = 0; n < 4; n++)
#pragma unroll
      for (int j = 0; j < 4; j++)
        Cp[(size_t)(m * 16 + j) * N + n * 16] = acc[m][n][j];
}

// ---------------- exact fp32 fallback (only if ws too small) ---------------
__global__ __launch_bounds__(256) void naive_gemm(const float* __restrict__ x,
                                                  const int* __restrict__ qw,
                                                  const int* __restrict__ qz,
                                                  const float* __restrict__ sc,
                                                  float* __restrict__ out) {
  __shared__ float xs[IN_F];
  int m = blockIdx.y;
  int n = blockIdx.x * 256 + threadIdx.x;
  for (int i = threadIdx.x; i < IN_F; i += 256) xs[i] = x[(size_t)m * IN_F + i];
  __syncthreads();
  float acc = 0.f;
  const int* qrow = qw + (size_t)n * (IN_F / 2);
  for (int g = 0; g < NGROUP; g++) {
    float z = (float)qz[n * NGROUP + g];
    float s = sc[n * NGROUP + g];
    for (int t = 0; t < 64; t++) {
      int q = qrow[g * 64 + t];
      acc += xs[g * 128 + 2 * t] * ((float)(q & 15) - z) * s;
      acc += xs[g * 128 + 2 * t + 1] * ((float)((q >> 4) & 15) - z) * s;
    }
  }
  out[(size_t)m * OUT_F + n] = acc;
}

extern "C" void kernel_launch(void* const* d_in, const int* in_sizes, int n_in,
                              void* d_out, int out_size, void* d_ws, size_t ws_size,
                              hipStream_t stream) {
  const float* x  = (const float*)d_in[0];
  const int*   qw = (const int*)d_in[1];
  const int*   qz = (const int*)d_in[2];
  const float* sc = (const float*)d_in[3];
  float* out = (float*)d_out;

  const size_t WBYTES = (size_t)OUT_F * IN_F * 2;
  const size_t XBYTES = (size_t)M_DIM * IN_F * 2;

  if (ws_size >= WBYTES + XBYTES) {
    u16* Wb = (u16*)d_ws;
    u16* Xb = (u16*)((char*)d_ws + WBYTES);
    dequant_w<<<2048, 256, 0, stream>>>(qw, qz, sc, Wb);
    cvt_x<<<2048, 256, 0, stream>>>(x, Xb);
    gemm256<<<(M_DIM / 256) * (OUT_F / 256), 512, 0, stream>>>(Xb, Wb, out);
  } else {
    naive_gemm<<<dim3(OUT_F / 256, M_DIM), 256, 0, stream>>>(x, qw, qz, sc, out);
  }
}